// Round 9
// baseline (385.340 us; speedup 1.0000x reference)
//
#include <hip/hip_runtime.h>

// Orbitals_ent: sorted-occupancy gather.
// x: (2048, 256) int32 in {-1,+1}
// orbitals_mf: (512, 256) f32, orbitals_hf: (512, 64) f32
// out: (2048, 256, 320) f32 = orbitals_full[idx], idx = ascending indices of
// occupied spin-orbitals (ups first, then downs, each ascending by site).
//
// R1: row-gather from L2, 132 us (5.1 TB/s write; fill-kernel ceiling 6.7).
// R2: nontemporal stores (builtin nt hint): neutral (134 us).
// R3: LDS column slices — FAILED (hf output offset bug).
// R4: R3 fixed: 139 us -> read-interference theory dead.
// R5: reg-batched loads + address-ordered stores: 128 us (BEST).
// R6: narrowed write front (512 x 1024): 132 us -> page-locality theory dead.
// R7/R8: L2-bypass stores (flat sc0sc1 / SRSRC sc1): FAILED correctness —
//     harness memset leaves dirty zero lines in L2 that evict later over our
//     HBM-written data. L2 bypass is structurally unsafe here. Closed.
// R9: DIAGNOSTIC — R5 with gather+store phase repeated 4x (idempotent).
//     ~512 us makes our dispatch #1 in top-5 so we finally see OUR
//     FETCH_SIZE/WRITE_SIZE. Branch: FETCH small -> R5 is roofline;
//     FETCH large -> reads are the thief, eliminate them next.

#define NBATCH 2048
#define NS 256   // sites (= rows gathered per batch)
#define NMF 256  // mf columns
#define NHF 64   // hf columns
#define NROW 320 // NMF + NHF
#define NREP 4   // diagnostic repetition factor

typedef float v4f __attribute__((ext_vector_type(4)));

__global__ __launch_bounds__(256) void gather_orbitals(
    const int* __restrict__ x,
    const float* __restrict__ mf,
    const float* __restrict__ hf,
    float* __restrict__ out)
{
    __shared__ int src[NS];   // dest row -> source spin-orbital row
    __shared__ int wtot[4];   // per-wave up counts

    const int b    = blockIdx.x;
    const int tid  = threadIdx.x;
    const int wave = tid >> 6;
    const int lane = tid & 63;

    // --- build dest->src permutation via prefix-sum of up-occupancy ---
    const int xv = x[(size_t)b * NS + tid];
    const bool up = (xv == 1);
    const unsigned long long m = __ballot(up);             // 64-bit on CDNA
    const int lane_ex = __popcll(m & ((1ull << lane) - 1ull));
    if (lane == 0) wtot[wave] = __popcll(m);
    __syncthreads();

    int woff = 0, nup = 0;
#pragma unroll
    for (int w = 0; w < 4; ++w) {
        const int c = wtot[w];
        if (w < wave) woff += c;
        nup += c;
    }
    const int upex = woff + lane_ex;          // #ups among sites < tid
    const int dest = up ? upex : (nup + (tid - upex));
    src[dest] = up ? tid : (NS + tid);
    __syncthreads();

    float* outb = out + (size_t)b * NS * NROW;
    const int j16 = lane >> 4;   // which of 4 rows this lane's hf chunk feeds
    const int l16 = lane & 15;   // float4 index within a 64-float hf tail

    // --- diagnostic: repeat the whole gather+store phase NREP times ---
#pragma unroll 1
    for (int rep = 0; rep < NREP; ++rep) {
        // 8 supersteps x 4 waves x 8 contiguous rows
#pragma unroll 1
        for (int ss = 0; ss < 8; ++ss) {
            const int rbase = ss * 32 + wave * 8;

            int s[8];
#pragma unroll
            for (int k = 0; k < 8; ++k) s[k] = src[rbase + k];

            v4f vm[8];
#pragma unroll
            for (int k = 0; k < 8; ++k)
                vm[k] = ((const v4f*)(mf + (size_t)s[k] * NMF))[lane];

            const int sh0 = src[rbase + j16];
            const int sh1 = src[rbase + 4 + j16];
            const v4f vh0 = ((const v4f*)(hf + (size_t)sh0 * NHF))[l16];
            const v4f vh1 = ((const v4f*)(hf + (size_t)sh1 * NHF))[l16];

            // stores in strict address order: rows rbase..+3 fully, then +4..+7
#pragma unroll
            for (int k = 0; k < 4; ++k)
                ((v4f*)(outb + (size_t)(rbase + k) * NROW))[lane] = vm[k];
            ((v4f*)(outb + (size_t)(rbase + j16) * NROW + NMF))[l16] = vh0;
#pragma unroll
            for (int k = 4; k < 8; ++k)
                ((v4f*)(outb + (size_t)(rbase + k) * NROW))[lane] = vm[k];
            ((v4f*)(outb + (size_t)(rbase + 4 + j16) * NROW + NMF))[l16] = vh1;
        }
    }
}

extern "C" void kernel_launch(void* const* d_in, const int* in_sizes, int n_in,
                              void* d_out, int out_size, void* d_ws, size_t ws_size,
                              hipStream_t stream) {
    const int*   x  = (const int*)d_in[0];
    const float* mf = (const float*)d_in[1];
    const float* hf = (const float*)d_in[2];
    float* out = (float*)d_out;

    gather_orbitals<<<dim3(NBATCH), dim3(256), 0, stream>>>(x, mf, hf, out);
}

// Round 10
// 127.375 us; speedup vs baseline: 3.0252x; 3.0252x over previous
//
#include <hip/hip_runtime.h>

// Orbitals_ent: sorted-occupancy gather.
// x: (2048, 256) int32 in {-1,+1}
// orbitals_mf: (512, 256) f32, orbitals_hf: (512, 64) f32
// out: (2048, 256, 320) f32 = orbitals_full[idx], idx = ascending indices of
// occupied spin-orbitals (ups first, then downs, each ascending by site).
//
// R1: row-gather from L2, 132 us (5.1 TB/s write).
// R2: nontemporal stores (builtin nt hint): neutral (134 us).
// R3: LDS column slices — FAILED (hf output offset bug).
// R4: R3 fixed: 139 us -> read-interference theory dead.
// R5: reg-batched loads + address-ordered stores: 128 us (BEST).
// R6: narrowed write front (512 x 1024): 132 us -> page-locality theory dead.
// R7/R8: L2-bypass stores: FAILED correctness — harness memset leaves dirty
//     zero lines in L2 that evict later over HBM-written data. Closed.
// R9: 4x-rep diagnostic: 385 us (96/rep) — marginal 86 us/rep is
//     MALL-absorption artifact (reps rewrite 256MB-resident lines), NOT
//     headroom. Fill's 6.7 TB/s similarly MALL-inflated (6 back-to-back
//     fills of the same buffer; TCC WRITE_SIZE counts L2->fabric incl MALL
//     hits). Conclusion: ~5.25 TB/s is the pure-write DRAM wall.
// R10: revert to R5. 671 MB / 5.25 TB/s ~= 128 us = roofline.

#define NBATCH 2048
#define NS 256   // sites (= rows gathered per batch)
#define NMF 256  // mf columns
#define NHF 64   // hf columns
#define NROW 320 // NMF + NHF

typedef float v4f __attribute__((ext_vector_type(4)));

__global__ __launch_bounds__(256) void gather_orbitals(
    const int* __restrict__ x,
    const float* __restrict__ mf,
    const float* __restrict__ hf,
    float* __restrict__ out)
{
    __shared__ int src[NS];   // dest row -> source spin-orbital row
    __shared__ int wtot[4];   // per-wave up counts

    const int b    = blockIdx.x;
    const int tid  = threadIdx.x;
    const int wave = tid >> 6;
    const int lane = tid & 63;

    // --- build dest->src permutation via prefix-sum of up-occupancy ---
    const int xv = x[(size_t)b * NS + tid];
    const bool up = (xv == 1);
    const unsigned long long m = __ballot(up);             // 64-bit on CDNA
    const int lane_ex = __popcll(m & ((1ull << lane) - 1ull));
    if (lane == 0) wtot[wave] = __popcll(m);
    __syncthreads();

    int woff = 0, nup = 0;
#pragma unroll
    for (int w = 0; w < 4; ++w) {
        const int c = wtot[w];
        if (w < wave) woff += c;
        nup += c;
    }
    const int upex = woff + lane_ex;          // #ups among sites < tid
    const int dest = up ? upex : (nup + (tid - upex));
    src[dest] = up ? tid : (NS + tid);
    __syncthreads();

    float* outb = out + (size_t)b * NS * NROW;
    const int j16 = lane >> 4;   // which of 4 rows this lane's hf chunk feeds
    const int l16 = lane & 15;   // float4 index within a 64-float hf tail

    // --- 8 supersteps x 4 waves x 8 contiguous rows ---
    for (int ss = 0; ss < 8; ++ss) {
        const int rbase = ss * 32 + wave * 8;

        int s[8];
#pragma unroll
        for (int k = 0; k < 8; ++k) s[k] = src[rbase + k];

        v4f vm[8];
#pragma unroll
        for (int k = 0; k < 8; ++k)
            vm[k] = ((const v4f*)(mf + (size_t)s[k] * NMF))[lane];

        const int sh0 = src[rbase + j16];
        const int sh1 = src[rbase + 4 + j16];
        const v4f vh0 = ((const v4f*)(hf + (size_t)sh0 * NHF))[l16];
        const v4f vh1 = ((const v4f*)(hf + (size_t)sh1 * NHF))[l16];

        // stores in strict address order: rows rbase..rbase+3 fully, then +4..+7
#pragma unroll
        for (int k = 0; k < 4; ++k)
            ((v4f*)(outb + (size_t)(rbase + k) * NROW))[lane] = vm[k];
        ((v4f*)(outb + (size_t)(rbase + j16) * NROW + NMF))[l16] = vh0;
#pragma unroll
        for (int k = 4; k < 8; ++k)
            ((v4f*)(outb + (size_t)(rbase + k) * NROW))[lane] = vm[k];
        ((v4f*)(outb + (size_t)(rbase + 4 + j16) * NROW + NMF))[l16] = vh1;
    }
}

extern "C" void kernel_launch(void* const* d_in, const int* in_sizes, int n_in,
                              void* d_out, int out_size, void* d_ws, size_t ws_size,
                              hipStream_t stream) {
    const int*   x  = (const int*)d_in[0];
    const float* mf = (const float*)d_in[1];
    const float* hf = (const float*)d_in[2];
    float* out = (float*)d_out;

    gather_orbitals<<<dim3(NBATCH), dim3(256), 0, stream>>>(x, mf, hf, out);
}